// Round 5
// baseline (303.544 us; speedup 1.0000x reference)
//
#include <hip/hip_runtime.h>

#define HW_DIM 4096
#define NHW 16            // hw positions per block
#define NT 256            // threads: 16 hw x 16 d-pairs
#define NCHUNK (HW_DIM / NHW)   // 256

// v_s: flat [16][72 float4] = [16][288 floats], XOR-swizzled in float4 units:
//   element (hwl, r) lives at f4 index hwl*72 + ((r>>2) ^ (hwl&7)), sub-offset r&3.
//   -> staging writes are aligned ds_write_b128, conflict-free;
//   -> compute reads float2 at base + j*128B immediate offsets, <=4-way (cheap).
// lp_s: flat [16][81] floats, staged by float4, softmax runs in-place.

__global__ __launch_bounds__(NT, 6)
void attn9_kernel(const float* __restrict__ logits,
                  const float* __restrict__ v,
                  float* __restrict__ out)
{
    __shared__ float v_s[NHW * 288];    // 18,432 B
    __shared__ float lp_s[NHW * 81];    //  5,184 B   (total 23,616 B -> 6 blocks/CU)

    const int t = threadIdx.x;
    const int bid = blockIdx.x;
    const int chunk = bid & (NCHUNK - 1);   // 0..255
    const int bh = bid >> 8;                // b*8 + h, 0..31

    const int hw0 = bh * HW_DIM + chunk * NHW;

    // ---- stage V: coalesced float4 global reads -> swizzled aligned f4 LDS writes ----
    {
        const float4* vg = reinterpret_cast<const float4*>(v + (size_t)hw0 * 288);
        float4* vs4 = reinterpret_cast<float4*>(v_s);
        #pragma unroll
        for (int k = 0; k < 5; ++k) {
            int idx4 = t + k * NT;                 // 0..1151 (16*288/4)
            if (idx4 < (NHW * 288) / 4) {
                float4 val = vg[idx4];
                int hwl = idx4 / 72;               // 72 f4 per hw row
                int q   = idx4 - hwl * 72;
                vs4[hwl * 72 + (q ^ (hwl & 7))] = val;
            }
        }
    }

    // ---- stage logits: coalesced float4 -> flat LDS ----
    {
        const float4* lg4 = reinterpret_cast<const float4*>(logits + (size_t)hw0 * 81);
        float4* ls4 = reinterpret_cast<float4*>(lp_s);
        #pragma unroll
        for (int k = 0; k < 2; ++k) {
            int idx4 = t + k * NT;                 // 0..323 (16*81/4 = 324)
            if (idx4 < (NHW * 81) / 4) ls4[idx4] = lg4[idx4];
        }
    }

    __syncthreads();

    // ---- softmax in-place: thread t < 144 owns row (hwl, i) ----
    if (t < NHW * 9) {
        const int hwl = t / 9;
        const int i = t - hwl * 9;
        float* row = &lp_s[hwl * 81 + i * 9];
        float x[9];
        #pragma unroll
        for (int j = 0; j < 9; ++j) x[j] = row[j] * 0.17677669529663687f;
        float m = x[0];
        #pragma unroll
        for (int j = 1; j < 9; ++j) m = fmaxf(m, x[j]);
        float e[9];
        float s = 0.f;
        #pragma unroll
        for (int j = 0; j < 9; ++j) { e[j] = expf(x[j] - m); s += e[j]; }
        const float inv = 1.0f / (s + 1e-12f);
        #pragma unroll
        for (int j = 0; j < 9; ++j) row[j] = e[j] * inv;
    }

    __syncthreads();

    // ---- compute: thread owns (hw, d-pair d0,d0+1); coalesced nt stores ----
    const int hw = t & (NHW - 1);       // 0..15
    const int dg = t >> 4;              // 0..15
    const int d0 = dg * 2;

    // swizzled v read base: f4 unit (d0>>2)^(hw&7), sub-offset (d0&3) floats
    const float2* vp = reinterpret_cast<const float2*>(
        reinterpret_cast<const char*>(v_s)
        + (size_t)hw * 1152                      // 288 floats * 4B
        + (((d0 >> 2) ^ (hw & 7)) << 4)          // swizzled f4 unit * 16B
        + ((d0 & 3) << 2));                      // 0 or 8 bytes
    float va[9], vb[9];
    #pragma unroll
    for (int j = 0; j < 9; ++j) {                // element j*32+d0 -> f4 unit j*8+...
        float2 vv = vp[j * 16];                  // j*128 bytes
        va[j] = vv.x; vb[j] = vv.y;
    }

    float* ob = out + (size_t)bh * 288 * HW_DIM + chunk * NHW + hw;
    const float* prow = &lp_s[hw * 81];
    #pragma unroll
    for (int i = 0; i < 9; ++i) {
        float a0 = 0.f, a1 = 0.f;
        #pragma unroll
        for (int j = 0; j < 9; ++j) {
            float p = prow[i * 9 + j];
            a0 = fmaf(p, va[j], a0);
            a1 = fmaf(p, vb[j], a1);
        }
        __builtin_nontemporal_store(a0, &ob[(size_t)(d0 * 9 + i) * HW_DIM]);
        __builtin_nontemporal_store(a1, &ob[(size_t)((d0 + 1) * 9 + i) * HW_DIM]);
    }
}

extern "C" void kernel_launch(void* const* d_in, const int* in_sizes, int n_in,
                              void* d_out, int out_size, void* d_ws, size_t ws_size,
                              hipStream_t stream) {
    const float* logits = (const float*)d_in[0];
    const float* v      = (const float*)d_in[1];
    float* out          = (float*)d_out;
    const int grid = 4 * 8 * NCHUNK;   // 8192 blocks
    attn9_kernel<<<grid, NT, 0, stream>>>(logits, v, out);
}

// Round 6
// 287.560 us; speedup vs baseline: 1.0556x; 1.0556x over previous
//
#include <hip/hip_runtime.h>

#define HW_DIM 4096
#define NHW 32            // hw positions per block
#define NT 512            // threads: 32 hw x 16 d-pairs
#define NCHUNK (HW_DIM / NHW)   // 128

// v_s: flat [32][72 float4] = [32][288 floats], XOR-swizzled in float4 units:
//   element (hwl, r) lives at f4 index hwl*72 + ((r>>2) ^ (hwl&7)), sub-off r&3.
//   -> staging writes are aligned ds_write_b128, conflict-free;
//   -> compute float2 reads at base + j*128B immediate offsets, ~2-way (free).
// lp_s: flat [32][81] floats, staged by float4, softmax in-place.
// Stores: wave = 32 hw x 2 d-groups -> 2x128B segments per store instr.

__global__ __launch_bounds__(NT)
void attn9_kernel(const float* __restrict__ logits,
                  const float* __restrict__ v,
                  float* __restrict__ out)
{
    __shared__ float v_s[NHW * 288];    // 36,864 B
    __shared__ float lp_s[NHW * 81];    // 10,368 B  (total 47,232 B -> 3 blocks/CU)

    const int t = threadIdx.x;
    const int bid = blockIdx.x;
    const int chunk = bid & (NCHUNK - 1);   // 0..127
    const int bh = bid >> 7;                // b*8 + h, 0..31

    const int hw0 = bh * HW_DIM + chunk * NHW;

    // ---- stage V: coalesced float4 global reads -> swizzled aligned f4 LDS writes ----
    {
        const float4* vg = reinterpret_cast<const float4*>(v + (size_t)hw0 * 288);
        float4* vs4 = reinterpret_cast<float4*>(v_s);
        #pragma unroll
        for (int k = 0; k < 5; ++k) {
            int idx4 = t + k * NT;                 // 0..2559, need 0..2303
            if (idx4 < (NHW * 288) / 4) {
                float4 val = vg[idx4];
                int hwl = idx4 / 72;               // 72 f4 per hw row
                int q   = idx4 - hwl * 72;
                vs4[hwl * 72 + (q ^ (hwl & 7))] = val;
            }
        }
    }

    // ---- stage logits: coalesced float4 -> flat LDS ----
    {
        const float4* lg4 = reinterpret_cast<const float4*>(logits + (size_t)hw0 * 81);
        float4* ls4 = reinterpret_cast<float4*>(lp_s);
        #pragma unroll
        for (int k = 0; k < 2; ++k) {
            int idx4 = t + k * NT;                 // need 0..647 (32*81/4)
            if (idx4 < (NHW * 81) / 4) ls4[idx4] = lg4[idx4];
        }
    }

    __syncthreads();

    // ---- softmax in-place: thread t < 288 owns row (hwl, i) ----
    if (t < NHW * 9) {
        const int hwl = t / 9;
        const int i = t - hwl * 9;
        float* row = &lp_s[hwl * 81 + i * 9];
        float x[9];
        #pragma unroll
        for (int j = 0; j < 9; ++j) x[j] = row[j] * 0.17677669529663687f;
        float m = x[0];
        #pragma unroll
        for (int j = 1; j < 9; ++j) m = fmaxf(m, x[j]);
        float e[9];
        float s = 0.f;
        #pragma unroll
        for (int j = 0; j < 9; ++j) { e[j] = expf(x[j] - m); s += e[j]; }
        const float inv = 1.0f / (s + 1e-12f);
        #pragma unroll
        for (int j = 0; j < 9; ++j) row[j] = e[j] * inv;
    }

    __syncthreads();

    // ---- compute: thread owns (hw, d-pair d0,d0+1); plain coalesced stores ----
    const int hw = t & (NHW - 1);       // 0..31
    const int dg = t >> 5;              // 0..15
    const int d0 = dg * 2;

    // swizzled v read base: f4 unit (d0>>2)^(hw&7), sub-offset (d0&3) floats
    const float2* vp = reinterpret_cast<const float2*>(
        reinterpret_cast<const char*>(v_s)
        + (size_t)hw * 1152                      // 288 floats * 4B
        + (((d0 >> 2) ^ (hw & 7)) << 4)          // swizzled f4 unit * 16B
        + ((d0 & 3) << 2));                      // 0 or 8 bytes
    float va[9], vb[9];
    #pragma unroll
    for (int j = 0; j < 9; ++j) {                // element j*32+d0 -> f4 unit j*8+...
        float2 vv = vp[j * 16];                  // j*128 bytes
        va[j] = vv.x; vb[j] = vv.y;
    }

    float* ob = out + (size_t)bh * 288 * HW_DIM + chunk * NHW + hw;
    const float* prow = &lp_s[hw * 81];
    #pragma unroll
    for (int i = 0; i < 9; ++i) {
        float a0 = 0.f, a1 = 0.f;
        #pragma unroll
        for (int j = 0; j < 9; ++j) {
            float p = prow[i * 9 + j];
            a0 = fmaf(p, va[j], a0);
            a1 = fmaf(p, vb[j], a1);
        }
        ob[(size_t)(d0 * 9 + i) * HW_DIM]       = a0;
        ob[(size_t)((d0 + 1) * 9 + i) * HW_DIM] = a1;
    }
}

extern "C" void kernel_launch(void* const* d_in, const int* in_sizes, int n_in,
                              void* d_out, int out_size, void* d_ws, size_t ws_size,
                              hipStream_t stream) {
    const float* logits = (const float*)d_in[0];
    const float* v      = (const float*)d_in[1];
    float* out          = (float*)d_out;
    const int grid = 4 * 8 * NCHUNK;   // 4096 blocks
    attn9_kernel<<<grid, NT, 0, stream>>>(logits, v, out);
}